// Round 6
// baseline (4666.687 us; speedup 1.0000x reference)
//
#include <hip/hip_runtime.h>
#include <math.h>

#define TSTEPS 1000
#define NS 512
#define HD 512
#define MWG 16
#define NWG 32
#define NTHREADS 256
#define APITCH 520                 // a_lds row pitch (elems); 1040B rows, 16B aligned
#define TSTRIDE (16*512)           // elems per tile in packed W (16 kbs)

typedef __attribute__((ext_vector_type(8))) short bf16x8;
typedef __attribute__((ext_vector_type(4))) float f32x4;

#define A_LDS_BYTES (MWG*APITCH*2)                 // 16640
#define OPART_BYTES (4*MWG*2*4)                    // 512
#define W_LDS_BYTES (32*4*512*2)                   // 131072 (kb 8..11, 32 tiles)
#define SMEM_BYTES  (A_LDS_BYTES + OPART_BYTES + W_LDS_BYTES)   // 148224

#define MFMA_ __builtin_amdgcn_mfma_f32_16x16x32_bf16

__device__ __forceinline__ unsigned short f2bf(float f) {
    union { float f; unsigned u; } v; v.f = f;
    unsigned u = v.u + 0x7FFFu + ((v.u >> 16) & 1u);
    return (unsigned short)(u >> 16);
}

__device__ __forceinline__ unsigned pkbf(float lo, float hi) {
    unsigned r;
    asm("v_cvt_pk_bf16_f32 %0, %1, %2" : "=v"(r) : "v"(lo), "v"(hi));
    return r;
}

__device__ __forceinline__ float relu_tanh(float x) {
    float xc = fminf(x, 10.0f);
    float e  = __builtin_amdgcn_exp2f(xc * 2.8853900817779268f);
    float t  = (e - 1.0f) * __builtin_amdgcn_rcpf(e + 1.0f);
    return fmaxf(t, 0.0f);
}

__device__ __forceinline__ void barrier_lds() {
    asm volatile("s_waitcnt lgkmcnt(0)\n\ts_barrier" ::: "memory");
}

// permuted-k -> source hidden index: k' = w*128 + c*8 + jj  ->  col = w*128 + jj*16 + c
__device__ __forceinline__ int srcrow(int k) {
    return (k & ~127) | ((k & 7) << 4) | ((k >> 3) & 15);
}

// ---------- pack 0.1*W_rec (k-permuted rows) into MFMA-B frags, tiles 0..31, kb 0..15 ----------
__global__ void pack_w(const float* __restrict__ Wrec, unsigned short* __restrict__ Wp) {
    int tid = blockIdx.x * 256 + threadIdx.x;      // 32 tiles * 16 kb * 64 lanes = 32768
    if (tid >= 32768) return;
    int lane = tid & 63, kb = (tid >> 6) & 15, tile = tid >> 10;
    int col = tile * 16 + (lane & 15);
    union { unsigned short s[8]; bf16x8 v; } buf;
#pragma unroll
    for (int b = 0; b < 8; ++b) {
        int k = kb * 32 + (lane >> 4) * 8 + b;
        buf.s[b] = f2bf(0.1f * Wrec[(size_t)srcrow(k) * HD + col]);
    }
    *(bf16x8*)(Wp + (size_t)tile * TSTRIDE + kb * 512 + lane * 8) = buf.v;
}

// ---------- persistent RNN: 4 waves; W in regs(kb0..5), LDS(kb8..11), L2-stream(kb6,7,12..15) ----------
// Output path: direct o_t = h_t @ W_out per step (f32 VALU + shuffle reduce) — round-1-proven.
__global__ __launch_bounds__(NTHREADS, 1)
void rnn4(const float* __restrict__ initdir, const float* __restrict__ vel,
          const float* __restrict__ fcw, const float* __restrict__ fcb,
          const float* __restrict__ W_in, const float* __restrict__ Wout,
          const float* __restrict__ bias,
          const unsigned short* __restrict__ Wp,
          float* __restrict__ out)
{
    extern __shared__ char smem[];
    unsigned short* a_lds = (unsigned short*)smem;
    float*          opart = (float*)(smem + A_LDS_BYTES);            // [4][16][2]
    unsigned short* w_lds = (unsigned short*)(smem + A_LDS_BYTES + OPART_BYTES);

    const int tid = threadIdx.x, lane = tid & 63, wv = tid >> 6;
    const int g = lane >> 4, c = lane & 15;
    const int i0 = blockIdx.x * MWG;

    // zero a_lds (cols 512..519 stay 0 forever)
    for (int i = tid; i < MWG * APITCH / 8; i += NTHREADS)
        *(uint4*)(a_lds + i * 8) = uint4{0u, 0u, 0u, 0u};

    // w_lds <- kbs 8..11 of all 32 tiles
    for (int i = tid; i < 8192; i += NTHREADS) {
        int ln = i & 63, b = i >> 6;            // b = tile*4 + (kb-8)
        int tile = b >> 2, kbr = b & 3;
        *(bf16x8*)(w_lds + b * 512 + ln * 8) =
            *(const bf16x8*)(Wp + (size_t)tile * TSTRIDE + (8 + kbr) * 512 + ln * 8);
    }

    // register-resident W: kbs 0..5, this wave's 8 tiles
    bf16x8 wreg[6][8];
#pragma unroll
    for (int kk = 0; kk < 6; ++kk)
#pragma unroll
        for (int jj = 0; jj < 8; ++jj)
            wreg[kk][jj] = *(const bf16x8*)(Wp + (size_t)(wv * 8 + jj) * TSTRIDE + kk * 512 + lane * 8);

    // per-lane invariants (0.1-prescaled input path; unscaled W_out)
    float win0[8], win1[8], bc[8], wo0[8], wo1[8];
    f32x4 acc[8];                      // holds 0.9*h between steps
    float av0[8][4];
#pragma unroll
    for (int jj = 0; jj < 8; ++jj) {
        int col = (wv * 8 + jj) * 16 + c;
        win0[jj] = 0.1f * W_in[col];
        win1[jj] = 0.1f * W_in[HD + col];
        bc[jj]   = 0.1f * bias[col];
        wo0[jj]  = Wout[2 * col];
        wo1[jj]  = Wout[2 * col + 1];
        float fw0 = fcw[2*col], fw1 = fcw[2*col+1], fb = fcb[col];
#pragma unroll
        for (int r = 0; r < 4; ++r) {
            int i = i0 + g * 4 + r;
            float h0 = initdir[2*i] * fw0 + initdir[2*i+1] * fw1 + fb;
            acc[jj][r] = 0.9f * h0;
            av0[jj][r] = relu_tanh(h0);
        }
    }

    __syncthreads();   // zero-fill + w_lds done

    // write a_0
    unsigned short* awr = a_lds + wv * 128 + c * 8;
#pragma unroll
    for (int r = 0; r < 4; ++r) {
        uint4 v;
        v.x = pkbf(av0[0][r], av0[1][r]); v.y = pkbf(av0[2][r], av0[3][r]);
        v.z = pkbf(av0[4][r], av0[5][r]); v.w = pkbf(av0[6][r], av0[7][r]);
        *(uint4*)(awr + (g * 4 + r) * APITCH) = v;
    }
    __syncthreads();

    const int rrow = tid >> 1, rd = tid & 1;

    // x prefetch for t=0 (rows g*4 .. g*4+3)
    f32x4 xa = *(const f32x4*)(vel + (size_t)(i0 + 4 * g) * 2);
    f32x4 xb = *(const f32x4*)(vel + (size_t)(i0 + 4 * g) * 2 + 4);

    const unsigned short* abase = a_lds + c * APITCH + g * 8;

#define PH_REG(kb) do { bf16x8 af = *(const bf16x8*)(abase + (kb)*32); \
    _Pragma("unroll") for (int jj = 0; jj < 8; ++jj) acc[jj] = MFMA_(af, wreg[kb][jj], acc[jj], 0,0,0); } while(0)

#define PH_LDS(kb) do { bf16x8 af = *(const bf16x8*)(abase + (kb)*32); \
    _Pragma("unroll") for (int jj = 0; jj < 8; ++jj) { \
        bf16x8 wf = *(const bf16x8*)(w_lds + ((wv*8+jj)*4 + ((kb)-8)) * 512 + lane * 8); \
        acc[jj] = MFMA_(af, wf, acc[jj], 0,0,0); } } while(0)

#define PH_STR(kb, S) do { bf16x8 af = *(const bf16x8*)(abase + (kb)*32); \
    _Pragma("unroll") for (int jj = 0; jj < 8; ++jj) acc[jj] = MFMA_(af, S[jj], acc[jj], 0,0,0); } while(0)

#define LOADS(S, kb) do { _Pragma("unroll") for (int jj = 0; jj < 8; ++jj) \
    S[jj] = *(const bf16x8*)(Wp + (size_t)(wv*8+jj) * TSTRIDE + (kb)*512 + lane*8); } while(0)

#pragma unroll 1
    for (int t = 0; t < TSTEPS; ++t) {
        // stream: issue kb6, kb7
        bf16x8 sA[8], sB[8];
        LOADS(sA, 6); LOADS(sB, 7);

        // write step t-1's output: o_{t-1} = h_{t-1} @ W_out (partials from prev iter)
        if (t > 0 && tid < 32) {
            float s = opart[rrow*2+rd] + opart[32+rrow*2+rd] + opart[64+rrow*2+rd] + opart[96+rrow*2+rd];
            out[((size_t)(t-1) * NS + i0 + rrow) * 2 + rd] = s;
        }

        PH_REG(0); PH_REG(1); PH_REG(2); PH_REG(3); PH_REG(4); PH_REG(5);
        PH_STR(6, sA);  LOADS(sA, 12);
        PH_STR(7, sB);  LOADS(sB, 13);
        PH_LDS(8); PH_LDS(9);
        PH_STR(12, sA); LOADS(sA, 14);
        PH_STR(13, sB); LOADS(sB, 15);
        PH_LDS(10); PH_LDS(11);
        PH_STR(14, sA);
        PH_STR(15, sB);

        // h update in f32 VALU: hn = acc + x0*win0 + x1*win1 + bc ; o-partials; acc <- 0.9*hn
        float x0[4] = {xa[0], xa[2], xb[0], xb[2]};
        float x1[4] = {xa[1], xa[3], xb[1], xb[3]};
        float p0[4] = {0.f,0.f,0.f,0.f}, p1[4] = {0.f,0.f,0.f,0.f};
        uint4 wval[4];
#pragma unroll
        for (int r = 0; r < 4; ++r) {
            float av[8];
#pragma unroll
            for (int jj = 0; jj < 8; ++jj) {
                float hn = acc[jj][r] + x0[r] * win0[jj] + x1[r] * win1[jj] + bc[jj];
                acc[jj][r] = 0.9f * hn;
                p0[r] += hn * wo0[jj];
                p1[r] += hn * wo1[jj];
                av[jj] = relu_tanh(hn);
            }
            wval[r].x = pkbf(av[0], av[1]); wval[r].y = pkbf(av[2], av[3]);
            wval[r].z = pkbf(av[4], av[5]); wval[r].w = pkbf(av[6], av[7]);
        }

        // reduce o-partials across the 16 lanes sharing g
#pragma unroll
        for (int m = 1; m <= 8; m <<= 1)
#pragma unroll
            for (int r = 0; r < 4; ++r) {
                p0[r] += __shfl_xor(p0[r], m, 64);
                p1[r] += __shfl_xor(p1[r], m, 64);
            }

        // x prefetch for t+1
        {
            int tn = (t + 1 < TSTEPS) ? (t + 1) : t;
            xa = *(const f32x4*)(vel + ((size_t)tn * NS + i0 + 4 * g) * 2);
            xb = *(const f32x4*)(vel + ((size_t)tn * NS + i0 + 4 * g) * 2 + 4);
        }

        barrier_lds();   // all reads of a_t done; out-writer done with opart

#pragma unroll
        for (int r = 0; r < 4; ++r)
            *(uint4*)(awr + (g * 4 + r) * APITCH) = wval[r];
        if (c == 0) {
#pragma unroll
            for (int r = 0; r < 4; ++r) {
                opart[wv * 32 + (g * 4 + r) * 2 + 0] = p0[r];
                opart[wv * 32 + (g * 4 + r) * 2 + 1] = p1[r];
            }
        }

        barrier_lds();   // a_{t+1} + o-partials visible
    }

    // epilogue: out[999]
    if (tid < 32) {
        float s = opart[rrow*2+rd] + opart[32+rrow*2+rd] + opart[64+rrow*2+rd] + opart[96+rrow*2+rd];
        out[((size_t)(TSTEPS-1) * NS + i0 + rrow) * 2 + rd] = s;
    }
}

extern "C" void kernel_launch(void* const* d_in, const int* in_sizes, int n_in,
                              void* d_out, int out_size, void* d_ws, size_t ws_size,
                              hipStream_t stream) {
    (void)in_sizes; (void)n_in; (void)out_size; (void)ws_size;
    const float* initdir = (const float*)d_in[0];
    const float* vel     = (const float*)d_in[1];
    const float* fc_w    = (const float*)d_in[2];
    const float* fc_b    = (const float*)d_in[3];
    const float* W_in    = (const float*)d_in[4];
    const float* W_rec   = (const float*)d_in[5];
    const float* W_out   = (const float*)d_in[6];
    const float* bias    = (const float*)d_in[7];
    float* out           = (float*)d_out;

    unsigned short* Wp = (unsigned short*)d_ws;   // 32 tiles * 16KB = 512KB

    pack_w<<<128, 256, 0, stream>>>(W_rec, Wp);

    hipFuncSetAttribute(reinterpret_cast<const void*>(&rnn4),
                        hipFuncAttributeMaxDynamicSharedMemorySize, SMEM_BYTES);

    rnn4<<<NWG, NTHREADS, SMEM_BYTES, stream>>>(
        initdir, vel, fc_w, fc_b, W_in, W_out, bias, Wp, out);
}

// Round 7
// 4402.737 us; speedup vs baseline: 1.0600x; 1.0600x over previous
//
#include <hip/hip_runtime.h>
#include <math.h>

#define TSTEPS 1000
#define NS 512
#define HD 512
#define MWG 16
#define NWG 32
#define NTHREADS 512
#define APITCH 520                 // a_lds row pitch (elems); 1040B rows
#define TSTRIDE (16*512)           // elems per tile in packed W (16 kbs)
#define ABUF (MWG*APITCH)          // elems per a buffer

typedef __attribute__((ext_vector_type(8))) short bf16x8;
typedef __attribute__((ext_vector_type(4))) float f32x4;

#define A_BYTES   (2*ABUF*2)                        // 33280 (double-buffered)
#define OP_BYTES  (2*8*MWG*2*4)                     // 2048  (double-buffered)
#define WL_BYTES  (32*3*512*2)                      // 98304 (kb 13..15, 32 tiles)
#define SMEM_BYTES (A_BYTES + OP_BYTES + WL_BYTES)  // 133632

#define MFMA_ __builtin_amdgcn_mfma_f32_16x16x32_bf16

__device__ __forceinline__ unsigned short f2bf(float f) {
    union { float f; unsigned u; } v; v.f = f;
    unsigned u = v.u + 0x7FFFu + ((v.u >> 16) & 1u);
    return (unsigned short)(u >> 16);
}

__device__ __forceinline__ unsigned pkbf(float lo, float hi) {
    unsigned r;
    asm("v_cvt_pk_bf16_f32 %0, %1, %2" : "=v"(r) : "v"(lo), "v"(hi));
    return r;
}

__device__ __forceinline__ float relu_tanh(float x) {
    float xc = fminf(x, 10.0f);
    float e  = __builtin_amdgcn_exp2f(xc * 2.8853900817779268f);
    float t  = (e - 1.0f) * __builtin_amdgcn_rcpf(e + 1.0f);
    return fmaxf(t, 0.0f);
}

__device__ __forceinline__ void barrier_lds() {
    asm volatile("s_waitcnt lgkmcnt(0)\n\ts_barrier" ::: "memory");
}

// round-2 permutation: permuted-k -> source hidden index
// k' = wv*64 + c*4 + jj  <->  col = wv*64 + jj*16 + c   (wave owns 4 tiles)
__device__ __forceinline__ int pi_inv(int k) {
    return (k & ~63) | ((k & 3) << 4) | ((k >> 2) & 15);
}

// ---------- pack 0.1*W_rec (pi-permuted rows) into MFMA-B frags, tiles 0..31, kb 0..15 ----------
__global__ void pack_w(const float* __restrict__ Wrec, unsigned short* __restrict__ Wp) {
    int tid = blockIdx.x * 512 + threadIdx.x;      // 32 tiles * 16 kb * 64 lanes = 32768
    if (tid >= 32768) return;
    int c  = tid & 15;
    int gg = (tid >> 4) & 3;
    int kb = (tid >> 6) & 15;
    int nt = tid >> 10;
    union { unsigned short s[8]; bf16x8 v; } buf;
#pragma unroll
    for (int b = 0; b < 8; ++b) {
        int k = kb * 32 + gg * 8 + b;
        buf.s[b] = f2bf(0.1f * Wrec[(size_t)pi_inv(k) * HD + nt * 16 + c]);
    }
    *(bf16x8*)(Wp + (size_t)tid * 8) = buf.v;
}

// ---------- tile 32: Wro = W_rec @ W_out (UNscaled, pi-permuted rows); extras = {Win@Wout, bias@Wout} ----------
__global__ void pack_wro(const float* __restrict__ Wrec, const float* __restrict__ Win,
                         const float* __restrict__ Wout, const float* __restrict__ bias,
                         unsigned short* __restrict__ Wp, float* __restrict__ extras) {
    __shared__ float wf[512][2];
    int tid = threadIdx.x;    // 512
    {
        int sr = pi_inv(tid);
        float s0 = 0.f, s1 = 0.f;
        for (int h = 0; h < HD; ++h) {
            float w = Wrec[(size_t)sr * HD + h];
            s0 += w * Wout[2 * h]; s1 += w * Wout[2 * h + 1];
        }
        wf[tid][0] = s0; wf[tid][1] = s1;
    }
    __syncthreads();
    for (int i = tid; i < 16 * 64; i += 512) {
        int lane = i & 63, kb = i >> 6, cc = lane & 15;
        union { unsigned short s[8]; bf16x8 v; } buf;
#pragma unroll
        for (int b = 0; b < 8; ++b) {
            int k = kb * 32 + (lane >> 4) * 8 + b;
            buf.s[b] = (cc < 2) ? f2bf(wf[k][cc]) : (unsigned short)0;
        }
        *(bf16x8*)(Wp + (size_t)32 * TSTRIDE + kb * 512 + lane * 8) = buf.v;
    }
    // extras[0..3] = Wio[di][d] (idx di*2+d), extras[4..5] = bo[d]  (UNscaled)
    if (tid < 6) {
        int d = tid & 1;
        float s = 0.f;
        if (tid < 4) {
            const float* src = Win + (tid >> 1) * HD;
            for (int h = 0; h < HD; ++h) s += src[h] * Wout[2 * h + d];
        } else {
            for (int h = 0; h < HD; ++h) s += bias[h] * Wout[2 * h + d];
        }
        extras[tid] = s;
    }
}

// ---------- persistent RNN: 8 waves; W fully resident: regs(kb0..12) + LDS(kb13..15); no stream ----------
__global__ __launch_bounds__(NTHREADS, 1)
void rnn8(const float* __restrict__ initdir, const float* __restrict__ vel,
          const float* __restrict__ fcw, const float* __restrict__ fcb,
          const float* __restrict__ W_in, const float* __restrict__ Wout,
          const float* __restrict__ bias,
          const unsigned short* __restrict__ Wp, const float* __restrict__ extras,
          float* __restrict__ out)
{
    extern __shared__ char smem[];
    unsigned short* a_lds = (unsigned short*)smem;                        // [2][16][520]
    float*          opart = (float*)(smem + A_BYTES);                     // [2][8][16][2]
    unsigned short* w_lds = (unsigned short*)(smem + A_BYTES + OP_BYTES); // [32*3][512]

    const int tid = threadIdx.x, lane = tid & 63, wv = tid >> 6;
    const int g = lane >> 4, c = lane & 15;
    const int i0 = blockIdx.x * MWG;

    // w_lds <- kbs 13..15 of all 32 tiles
    for (int i = tid; i < 6144; i += NTHREADS) {
        int ln = i & 63, b = i >> 6;            // b = tile*3 + (kb-13)
        int tile = b / 3, kbr = b % 3;
        *(bf16x8*)(w_lds + b * 512 + ln * 8) =
            *(const bf16x8*)(Wp + (size_t)tile * TSTRIDE + (13 + kbr) * 512 + ln * 8);
    }

    // register-resident W: kbs 0..12, this wave's 4 tiles
    bf16x8 wreg[13][4];
#pragma unroll
    for (int kk = 0; kk < 13; ++kk)
#pragma unroll
        for (int jj = 0; jj < 4; ++jj)
            wreg[kk][jj] = *(const bf16x8*)(Wp + (size_t)(wv * 4 + jj) * TSTRIDE + kk * 512 + lane * 8);
    bf16x8 wro[2];
#pragma unroll
    for (int s = 0; s < 2; ++s)
        wro[s] = *(const bf16x8*)(Wp + (size_t)32 * TSTRIDE + (2 * wv + s) * 512 + lane * 8);

    // per-lane invariants (0.1-prescaled input path); h0
    float win0[4], win1[4], bc[4];
    f32x4 acc[4];                      // holds 0.9*h between steps (MFMA C)
    float av0[4][4];
    float p0[4] = {0.f,0.f,0.f,0.f}, p1[4] = {0.f,0.f,0.f,0.f};
#pragma unroll
    for (int jj = 0; jj < 4; ++jj) {
        int col = (wv * 4 + jj) * 16 + c;
        win0[jj] = 0.1f * W_in[col];
        win1[jj] = 0.1f * W_in[HD + col];
        bc[jj]   = 0.1f * bias[col];
        float wo0 = Wout[2 * col], wo1 = Wout[2 * col + 1];
        float fw0 = fcw[2*col], fw1 = fcw[2*col+1], fb = fcb[col];
#pragma unroll
        for (int r = 0; r < 4; ++r) {
            int i = i0 + g * 4 + r;
            float h0 = initdir[2*i] * fw0 + initdir[2*i+1] * fw1 + fb;
            acc[jj][r] = 0.9f * h0;
            p0[r] += h0 * wo0; p1[r] += h0 * wo1;
            av0[jj][r] = relu_tanh(h0);
        }
    }
#pragma unroll
    for (int m = 1; m <= 8; m <<= 1)
#pragma unroll
        for (int r = 0; r < 4; ++r) {
            p0[r] += __shfl_xor(p0[r], m, 64);
            p1[r] += __shfl_xor(p1[r], m, 64);
        }

    __syncthreads();   // w_lds ready

    // write a_0 into buffer 0, o-partials(h0) into opart[0]
    {
        unsigned short* aw0 = a_lds + wv * 64 + 4 * c;
#pragma unroll
        for (int r = 0; r < 4; ++r) {
            uint2 v;
            v.x = pkbf(av0[0][r], av0[1][r]);
            v.y = pkbf(av0[2][r], av0[3][r]);
            *(uint2*)(aw0 + (g * 4 + r) * APITCH) = v;
        }
        if (c == 0) {
#pragma unroll
            for (int r = 0; r < 4; ++r) {
                opart[wv * 32 + (g * 4 + r) * 2 + 0] = p0[r];
                opart[wv * 32 + (g * 4 + r) * 2 + 1] = p1[r];
            }
        }
    }
    __syncthreads();

    // reducer state (tid<32): o_0 = h0 @ W_out
    const int rrow = tid >> 1, rd = tid & 1;
    float o_state = 0.f, wio_x = 0.f, wio_y = 0.f, bo_d = 0.f;
    float2 oxv = make_float2(0.f, 0.f);
    if (tid < 32) {
        float s = 0.f;
#pragma unroll
        for (int w = 0; w < 8; ++w) s += opart[w * 32 + rrow * 2 + rd];
        o_state = s;
        wio_x = extras[rd]; wio_y = extras[2 + rd]; bo_d = extras[4 + rd];
    }

    // x prefetch for t=0 (rows 4g..4g+3)
    f32x4 xa = *(const f32x4*)(vel + (size_t)(i0 + 4 * g) * 2);
    f32x4 xb = *(const f32x4*)(vel + (size_t)(i0 + 4 * g) * 2 + 4);

#define PH_REG(kb) do { bf16x8 af = *(const bf16x8*)(ab + (kb)*32); \
    _Pragma("unroll") for (int jj = 0; jj < 4; ++jj) acc[jj] = MFMA_(af, wreg[kb][jj], acc[jj], 0,0,0); } while(0)

#define PH_LDS(kb) do { bf16x8 af = *(const bf16x8*)(ab + (kb)*32); \
    _Pragma("unroll") for (int jj = 0; jj < 4; ++jj) { \
        bf16x8 wf = *(const bf16x8*)(w_lds + ((wv*4+jj)*3 + ((kb)-13)) * 512 + lane * 8); \
        acc[jj] = MFMA_(af, wf, acc[jj], 0,0,0); } } while(0)

#pragma unroll 1
    for (int t = 0; t < TSTEPS; ++t) {
        const int pb = t & 1;
        const unsigned short* ab = a_lds + pb * ABUF + c * APITCH + g * 8;
        unsigned short*       aw = a_lds + (pb ^ 1) * ABUF + wv * 64 + 4 * c;
        const float* opr = opart + pb * 256;
        float*       opw = opart + (pb ^ 1) * 256;

        // finish step t-1's output (overlaps other waves' MFMA phase)
        if (tid < 32) {
            if (t > 0) {
                float s = 0.f;
#pragma unroll
                for (int w = 0; w < 8; ++w) s += opr[w * 32 + rrow * 2 + rd];
                o_state = 0.9f * o_state + 0.1f * (s + oxv.x * wio_x + oxv.y * wio_y + bo_d);
                out[((size_t)(t - 1) * NS + i0 + rrow) * 2 + rd] = o_state;
            }
            oxv = *(const float2*)(vel + ((size_t)t * NS + i0 + rrow) * 2);   // for t+1
        }

        // main MFMA: 16 kbs, W from regs + LDS (no stream)
        PH_REG(0); PH_REG(1); PH_REG(2); PH_REG(3);
        PH_LDS(13);
        PH_REG(4); PH_REG(5); PH_REG(6); PH_REG(7);
        PH_LDS(14);
        PH_REG(8); PH_REG(9); PH_REG(10); PH_REG(11);
        PH_LDS(15);
        PH_REG(12);

        // o-partials: this wave's 2 k-blocks against Wro (round-2 scheme)
        f32x4 acco = {0.f, 0.f, 0.f, 0.f};
#pragma unroll
        for (int s = 0; s < 2; ++s) {
            bf16x8 af = *(const bf16x8*)(ab + (2 * wv + s) * 32);
            acco = MFMA_(af, wro[s], acco, 0, 0, 0);
        }

        // h update in f32 VALU: hn = acc + x0*win0' + x1*win1' + bc' ; acc <- 0.9*hn
        float x0[4] = {xa[0], xa[2], xb[0], xb[2]};
        float x1[4] = {xa[1], xa[3], xb[1], xb[3]};
        uint2 wval[4];
#pragma unroll
        for (int r = 0; r < 4; ++r) {
            float av[4];
#pragma unroll
            for (int jj = 0; jj < 4; ++jj) {
                float hn = acc[jj][r] + x0[r] * win0[jj] + x1[r] * win1[jj] + bc[jj];
                acc[jj][r] = 0.9f * hn;
                av[jj] = relu_tanh(hn);
            }
            wval[r].x = pkbf(av[0], av[1]);
            wval[r].y = pkbf(av[2], av[3]);
        }

        // x prefetch for t+1 (stays in flight across the barrier)
        {
            int tn = (t + 1 < TSTEPS) ? (t + 1) : t;
            xa = *(const f32x4*)(vel + ((size_t)tn * NS + i0 + 4 * g) * 2);
            xb = *(const f32x4*)(vel + ((size_t)tn * NS + i0 + 4 * g) * 2 + 4);
        }

        // write a_{t+1} + o-partials into the OTHER buffers (safe pre-barrier: readers
        // of these buffers finished at the end-of-(t-1) barrier)
#pragma unroll
        for (int r = 0; r < 4; ++r)
            *(uint2*)(aw + (g * 4 + r) * APITCH) = wval[r];
        if (c < 2) {
#pragma unroll
            for (int r = 0; r < 4; ++r)
                opw[wv * 32 + (g * 4 + r) * 2 + c] = acco[r];
        }

        barrier_lds();   // single barrier per step
    }

    // epilogue: out[999]  (step 999 wrote opart[0]; oxv = vel[999])
    if (tid < 32) {
        const float* opr = opart + (TSTEPS & 1) * 256;
        float s = 0.f;
#pragma unroll
        for (int w = 0; w < 8; ++w) s += opr[w * 32 + rrow * 2 + rd];
        o_state = 0.9f * o_state + 0.1f * (s + oxv.x * wio_x + oxv.y * wio_y + bo_d);
        out[((size_t)(TSTEPS - 1) * NS + i0 + rrow) * 2 + rd] = o_state;
    }
}

extern "C" void kernel_launch(void* const* d_in, const int* in_sizes, int n_in,
                              void* d_out, int out_size, void* d_ws, size_t ws_size,
                              hipStream_t stream) {
    (void)in_sizes; (void)n_in; (void)out_size; (void)ws_size;
    const float* initdir = (const float*)d_in[0];
    const float* vel     = (const float*)d_in[1];
    const float* fc_w    = (const float*)d_in[2];
    const float* fc_b    = (const float*)d_in[3];
    const float* W_in    = (const float*)d_in[4];
    const float* W_rec   = (const float*)d_in[5];
    const float* W_out   = (const float*)d_in[6];
    const float* bias    = (const float*)d_in[7];
    float* out           = (float*)d_out;

    unsigned short* Wp = (unsigned short*)d_ws;                             // 33 tiles * 16KB = 528KB
    float* extras      = (float*)((char*)d_ws + (size_t)33 * TSTRIDE * 2);  // 6 floats

    pack_w<<<64, 512, 0, stream>>>(W_rec, Wp);
    pack_wro<<<1, 512, 0, stream>>>(W_rec, W_in, W_out, bias, Wp, extras);

    hipFuncSetAttribute(reinterpret_cast<const void*>(&rnn8),
                        hipFuncAttributeMaxDynamicSharedMemorySize, SMEM_BYTES);

    rnn8<<<NWG, NTHREADS, SMEM_BYTES, stream>>>(
        initdir, vel, fc_w, fc_b, W_in, W_out, bias, Wp, extras, out);
}